// Round 5
// baseline (378.285 us; speedup 1.0000x reference)
//
#include <hip/hip_runtime.h>
#include <stdint.h>

typedef __attribute__((ext_vector_type(4))) int i32x4;
typedef __attribute__((ext_vector_type(8))) int i32x8;
typedef __attribute__((ext_vector_type(16))) float f32x16;

#define BM 128
#define BN 128
// Quantized operands live in global memory in MFMA-FRAGMENT ORDER:
//   fragment = 32 consecutive K-elements of one row, packed to 16 B (fp4 signs).
//   u32 index o(row,k32,wrd) = (((row>>5)*kbT + (k32>>2))*128 + (k32&3)*32 + (row&31))*4 + wrd
//   where k32 = k/32, wrd = (k/8)&3, kbT = K/128.
// Producer: one wave-pass reads 2 KB CONTIGUOUS of one row (lane i: 32-B pair at
// +i*32), packs 8 elems -> 1 u32, stores at o (16-B quad granularity, scattered
// only within an 8-KB window whose 32 row-writers are all in the same block ->
// L2 write-merge is clean). Reads perfectly linear, writes block-local.

// fp4 e2m1 signs: +1 = 0x2, -1 = 0xA, 0 = 0x0 (matches jnp.sign exactly)
__device__ __forceinline__ uint32_t nib4(float v) {
  return v > 0.f ? 0x2u : (v < 0.f ? 0xAu : 0u);
}

// 8 fp32 -> 8 nibbles in one u32 (element j -> nibble j, low nibble first)
__device__ __forceinline__ uint32_t pack8(float4 a, float4 b) {
  return nib4(a.x) | (nib4(a.y) << 4) | (nib4(a.z) << 8) | (nib4(a.w) << 12) |
         (nib4(b.x) << 16) | (nib4(b.y) << 20) | (nib4(b.z) << 24) | (nib4(b.w) << 28);
}

__device__ __forceinline__ float abs4(float4 v) {
  return fabsf(v.x) + fabsf(v.y) + fabsf(v.z) + fabsf(v.w);
}

// ---------------- fused quantize -> fragment-ordered fp4 ----------------
// Blocks [0, wBlocks): weight rowblock (32 rows x full K) + mean|w| scale
//   (full-wave shfl_xor reduce per row; no LDS, no atomics).
// Blocks [wBlocks, ...): x slab = 32 rows x 512 elements.
// Per wave-pass: row r, 512 elements; lane i packs elements i*8..i*8+8.
__global__ __launch_bounds__(256) void quant_fused_kernel(
    const float4* __restrict__ x, uint32_t* __restrict__ xq,
    const float4* __restrict__ w, uint32_t* __restrict__ wq,
    float* __restrict__ scale, int wBlocks, int K) {
  const int t = threadIdx.x;
  const int b = blockIdx.x;
  const int kbT = K >> 7;   // 32
  const int K4 = K >> 2;    // float4s per row
  const int lane = t & 63;
  const int wave = t >> 6;

  if (b < wBlocks) {
    // ---- weight rowblock b: rows [b*32, b*32+32), full K ----
    const int rowblk = b;
#pragma unroll
    for (int p = 0; p < 8; ++p) {
      const int r = wave * 8 + p;  // row-local 0..31
      const size_t row = (size_t)rowblk * 32 + r;
      const float4* rowp = w + row * K4;
      float rsum = 0.f;
      for (int ks = 0; ks < 8; ++ks) {  // 512-element k-slabs
        const float4* src = rowp + ks * 128 + lane * 2;
        float4 a = src[0], c = src[1];
        wq[((size_t)(rowblk * kbT + ks * 4 + (lane >> 4)) * 128 +
            ((lane >> 2) & 3) * 32 + r) * 4 + (lane & 3)] = pack8(a, c);
        rsum += abs4(a) + abs4(c);
      }
      for (int off = 1; off < 64; off <<= 1) rsum += __shfl_xor(rsum, off);
      if (lane == 0) scale[row] = rsum * (1.0f / (float)K);
    }
  } else {
    // ---- x slab: rowblock s>>3, k-slab s&7 (512 elements) ----
    const int s = b - wBlocks;
    const int rowblk = s >> 3;
    const int ks = s & 7;
#pragma unroll
    for (int p = 0; p < 8; ++p) {
      const int r = wave * 8 + p;
      const float4* src = x + ((size_t)rowblk * 32 + r) * K4 + ks * 128 + lane * 2;
      float4 a = src[0], c = src[1];
      xq[((size_t)(rowblk * kbT + ks * 4 + (lane >> 4)) * 128 +
          ((lane >> 2) & 3) * 32 + r) * 4 + (lane & 3)] = pack8(a, c);
    }
  }
}

// async global->LDS, 16B per lane (wave-uniform base + lane*16)
__device__ __forceinline__ void load16(const uint8_t* g, uint8_t* l) {
  __builtin_amdgcn_global_load_lds(
      (const __attribute__((address_space(1))) uint32_t*)(uintptr_t)g,
      (__attribute__((address_space(3))) uint32_t*)(uintptr_t)l,
      16, 0, 0);
}

// ---------------- GEMM: C[m,n] = scale[n] * sum_k A[m,k]*B[n,k] ----------------
// A, B in fragment order (see header comment). mfma_scale 32x32x64 f8f6f4, FMT=4,
// scales pinned to 1.0 (e8m0 0x7F). fp32 accumulate exact for +-1 sums.
// 256 threads = 4 waves in 2x2; each wave does 64x64 via 2x2 of 32x32 tiles.
__global__ __launch_bounds__(256, 3) void gemm_bt_kernel(
    const uint8_t* __restrict__ A, const uint8_t* __restrict__ B,
    const float* __restrict__ scale, float* __restrict__ C,
    int M, int N, int K) {
  __shared__ __align__(16) uint8_t As[BM * 64];  // 4 groups x 128 frags x 16 B
  __shared__ __align__(16) uint8_t Bs[BN * 64];

  const int tid = threadIdx.x;
  const int lane = tid & 63;
  const int wave = tid >> 6;
  const int waveM = wave & 1;
  const int waveN = wave >> 1;
  const int kbT = K >> 7;  // K-tile iterations (64 B of K per iter)

  // XCD-aware bijective swizzle (nwg = gridDim.x*gridDim.y, divisible by 8)
  const int nwg = gridDim.x * gridDim.y;
  const int id = blockIdx.y * gridDim.x + blockIdx.x;
  const int swz = (id & 7) * (nwg >> 3) + (id >> 3);
  const int bx = swz % gridDim.x;
  const int by = swz / gridDim.x;

  // staging: wave w owns 32-row group w; 2 contiguous 1024-B loads per K-iter
  const uint8_t* aG = A + ((size_t)(by * 4 + wave) * kbT) * 2048 + lane * 16;
  const uint8_t* bG = B + ((size_t)(bx * 4 + wave) * kbT) * 2048 + lane * 16;
  uint8_t* aL = As + wave * 2048 + lane * 16;
  uint8_t* bL = Bs + wave * 2048 + lane * 16;

  // fragment reads: group (2*waveM+mi), p2 = s*64 + lane  ->  lane-linear
  const uint8_t* aF = As + waveM * 4096 + lane * 16;
  const uint8_t* bF = Bs + waveN * 4096 + lane * 16;

  f32x16 acc[2][2] = {};
  // persistent v8i32 operands; high 4 regs stay zero (fp4 uses low 4 only)
  i32x8 aop[2] = {}, bop[2] = {};

  for (int i = 0; i < kbT; ++i) {
    __syncthreads();  // previous iter's LDS reads done before overwrite
    const size_t o = (size_t)i * 2048;
    load16(aG + o, aL);
    load16(aG + o + 1024, aL + 1024);
    load16(bG + o, bL);
    load16(bG + o + 1024, bL + 1024);
    __syncthreads();  // staging complete (vmcnt drained before barrier)

#pragma unroll
    for (int s = 0; s < 2; ++s) {  // two K=64 MFMA steps per 64-B row tile
#pragma unroll
      for (int mi = 0; mi < 2; ++mi) {
        i32x4 t4 = *(const i32x4*)(aF + mi * 2048 + s * 1024);
        aop[mi].s0 = t4.x; aop[mi].s1 = t4.y; aop[mi].s2 = t4.z; aop[mi].s3 = t4.w;
      }
#pragma unroll
      for (int ni = 0; ni < 2; ++ni) {
        i32x4 t4 = *(const i32x4*)(bF + ni * 2048 + s * 1024);
        bop[ni].s0 = t4.x; bop[ni].s1 = t4.y; bop[ni].s2 = t4.z; bop[ni].s3 = t4.w;
      }
#pragma unroll
      for (int mi = 0; mi < 2; ++mi)
#pragma unroll
        for (int ni = 0; ni < 2; ++ni)
          acc[mi][ni] = __builtin_amdgcn_mfma_scale_f32_32x32x64_f8f6f4(
              aop[mi], bop[ni], acc[mi][ni],
              /*cbsz=fp4*/ 4, /*blgp=fp4*/ 4,
              /*opsel_a*/ 0, 0x7f7f7f7f, /*opsel_b*/ 0, 0x7f7f7f7f);
    }
  }

  // epilogue: 32x32 C/D layout col=lane&31, row=(reg&3)+8*(reg>>2)+4*(lane>>5)
  const int cCol = bx * BN + waveN * 64 + (lane & 31);
  const int cRowBase = by * BM + waveM * 64 + 4 * (lane >> 5);
  float sc[2];
#pragma unroll
  for (int ni = 0; ni < 2; ++ni) sc[ni] = scale[cCol + ni * 32];
#pragma unroll
  for (int mi = 0; mi < 2; ++mi)
#pragma unroll
    for (int ni = 0; ni < 2; ++ni)
#pragma unroll
      for (int r = 0; r < 16; ++r) {
        int row = cRowBase + mi * 32 + (r & 3) + 8 * (r >> 2);
        C[(size_t)row * N + cCol + ni * 32] = acc[mi][ni][r] * sc[ni];
      }
}

// ---------------- fallback (only if ws too small): exact, slow ----------------
__global__ void fallback_gemm(const float* __restrict__ X, const float* __restrict__ W,
                              float* __restrict__ C, int M, int N, int K) {
  __shared__ float xs[16][65];
  __shared__ float ws[16][65];
  __shared__ float wabs[256];
  __shared__ float scl[16];
  const int tx = threadIdx.x, ty = threadIdx.y;
  const int t = ty * 16 + tx;
  float acc = 0.f, wa = 0.f;
  for (int k0 = 0; k0 < K; k0 += 64) {
    __syncthreads();
#pragma unroll
    for (int j = 0; j < 4; ++j) {
      int e = t * 4 + j;
      int r = e >> 6, c = e & 63;
      float xv = X[(size_t)(blockIdx.y * 16 + r) * K + k0 + c];
      xs[r][c] = xv > 0.f ? 1.f : (xv < 0.f ? -1.f : 0.f);
      float wv = W[(size_t)(blockIdx.x * 16 + r) * K + k0 + c];
      ws[r][c] = wv > 0.f ? 1.f : (wv < 0.f ? -1.f : 0.f);
      wa += fabsf(wv);
    }
    __syncthreads();
#pragma unroll 8
    for (int k = 0; k < 64; ++k) acc += xs[ty][k] * ws[tx][k];
  }
  wabs[t] = wa;
  __syncthreads();
  for (int s2 = 8; s2 > 0; s2 >>= 1) {
    if (tx < s2) wabs[t] += wabs[t + s2];
    __syncthreads();
  }
  if (tx == 0) scl[ty] = wabs[t] / (float)K;
  __syncthreads();
  C[(size_t)(blockIdx.y * 16 + ty) * N + (blockIdx.x * 16 + tx)] = acc * scl[tx];
}

extern "C" void kernel_launch(void* const* d_in, const int* in_sizes, int n_in,
                              void* d_out, int out_size, void* d_ws, size_t ws_size,
                              hipStream_t stream) {
  const float* x = (const float*)d_in[0];
  const float* w = (const float*)d_in[1];
  float* out = (float*)d_out;

  const int K = 4096;
  const int N = in_sizes[1] / K;  // 4096
  const int M = in_sizes[0] / K;  // 8192

  size_t need = (size_t)M * (K / 2) + (size_t)N * (K / 2) + (size_t)N * sizeof(float);
  if (ws_size >= need) {
    uint8_t* Xq = (uint8_t*)d_ws;
    uint8_t* Wq = Xq + (size_t)M * (K / 2);
    float* scale = (float*)(Wq + (size_t)N * (K / 2));

    const int wBlocks = N / 32;                              // 128 rowblocks
    const int xBlocks = (int)(((size_t)M * K) / 16384);      // 2048 slabs
    quant_fused_kernel<<<wBlocks + xBlocks, 256, 0, stream>>>(
        (const float4*)x, (uint32_t*)Xq, (const float4*)w, (uint32_t*)Wq,
        scale, wBlocks, K);

    dim3 grid(N / BN, M / BM);
    gemm_bt_kernel<<<grid, 256, 0, stream>>>(Xq, Wq, scale, out, M, N, K);
  } else {
    dim3 grid(N / 16, M / 16);
    fallback_gemm<<<grid, dim3(16, 16), 0, stream>>>(x, w, out, M, N, K);
  }
}

// Round 6
// 363.910 us; speedup vs baseline: 1.0395x; 1.0395x over previous
//
#include <hip/hip_runtime.h>
#include <stdint.h>

typedef __attribute__((ext_vector_type(4))) int i32x4;
typedef __attribute__((ext_vector_type(8))) int i32x8;
typedef __attribute__((ext_vector_type(16))) float f32x16;

#define BM 128
#define BN 128
// Quantized operands live in global memory in MFMA-FRAGMENT ORDER:
//   fragment = 32 consecutive K-elements of one row, packed to 16 B (fp4 signs).
//   u32 index o(row,k32,wrd) = (((row>>5)*kbT + (k32>>2))*128 + (k32&3)*32 + (row&31))*4 + wrd
//   where k32 = k/32, wrd = (k/8)&3, kbT = K/128.
// Producer: per 32-row x 512-elem slab, the fragment-order output is 8 KB
// CONTIGUOUS. Phase 1: lane reads a contiguous 32-B pair of one row, packs to
// one u32, ds_write at fragment-local slot (XOR-swizzled -> 2-way = free).
// Phase 2: uint4 LDS read at swizzled block index, lane-consecutive uint4
// global store. Both global sides fully coalesced; transpose lives in LDS.

// fp4 e2m1 signs: +1 = 0x2, -1 = 0xA, 0 = 0x0 (matches jnp.sign exactly)
__device__ __forceinline__ uint32_t nib4(float v) {
  return v > 0.f ? 0x2u : (v < 0.f ? 0xAu : 0u);
}

// 8 fp32 -> 8 nibbles in one u32 (element j -> nibble j, low nibble first)
__device__ __forceinline__ uint32_t pack8(float4 a, float4 b) {
  return nib4(a.x) | (nib4(a.y) << 4) | (nib4(a.z) << 8) | (nib4(a.w) << 12) |
         (nib4(b.x) << 16) | (nib4(b.y) << 20) | (nib4(b.z) << 24) | (nib4(b.w) << 28);
}

__device__ __forceinline__ float abs4(float4 v) {
  return fabsf(v.x) + fabsf(v.y) + fabsf(v.z) + fabsf(v.w);
}

// ---------------- fused quantize -> fragment-ordered fp4 ----------------
// Blocks [0, wBlocks): weight rowblock (32 rows x full K, 8 slab passes) + scale.
// Blocks [wBlocks, ...): x slab = 32 rows x 512 elements (one pass).
// Fragment-local u32 slot for (row r, lane i):
//   w = (i>>4)*512 + ((i>>2)&3)*128 + r*4 + (i&3);  swizzle: w ^ (((w>>7)&7)<<2)
//   where (w>>7)&7 == (i>>2)&7 on the write side, == blk>>5 on the read side.
__global__ __launch_bounds__(256) void quant_fused_kernel(
    const float4* __restrict__ x, uint4* __restrict__ xq,
    const float4* __restrict__ w, uint4* __restrict__ wq,
    float* __restrict__ scale, int wBlocks, int K) {
  __shared__ __align__(16) uint32_t lds[2048];  // 8 KB slab buffer
  const int t = threadIdx.x;
  const int b = blockIdx.x;
  const int K4 = K >> 2;   // float4s per row
  const int kbT = K >> 7;  // 32
  const int lane = t & 63;
  const int wave = t >> 6;
  const int wloc = (lane >> 4) * 512 + ((lane >> 2) & 3) * 128 + (lane & 3);
  const int swz = ((lane >> 2) & 7) << 2;

  if (b < wBlocks) {
    // ---- weight rowblock b: rows [b*32, b*32+32), 8 k-slabs of 512 ----
    const int rb = b;
    float rsum[8] = {0.f, 0.f, 0.f, 0.f, 0.f, 0.f, 0.f, 0.f};
    for (int ks = 0; ks < 8; ++ks) {
#pragma unroll
      for (int p = 0; p < 8; ++p) {
        const int r = wave * 8 + p;
        const float4* src = w + ((size_t)rb * 32 + r) * K4 + ks * 128 + lane * 2;
        float4 a = src[0], c = src[1];
        lds[(wloc + r * 4) ^ swz] = pack8(a, c);
        rsum[p] += abs4(a) + abs4(c);
      }
      __syncthreads();
      const size_t gbase = (size_t)rb * 4096 + ks * 512;  // uint4 units
#pragma unroll
      for (int q = 0; q < 2; ++q) {
        const int blk = q * 256 + t;
        const int sblk = blk ^ ((blk >> 5) & 7);
        wq[gbase + blk] = *(const uint4*)&lds[sblk * 4];
      }
      __syncthreads();
    }
#pragma unroll
    for (int p = 0; p < 8; ++p) {
      float s = rsum[p];
      for (int off = 1; off < 64; off <<= 1) s += __shfl_xor(s, off);
      if (lane == 0) scale[rb * 32 + wave * 8 + p] = s * (1.0f / (float)K);
    }
  } else {
    // ---- x slab: rowblock s>>3, k-slab s&7 ----
    const int s = b - wBlocks;
    const int rb = s >> 3;
    const int ks = s & 7;
#pragma unroll
    for (int p = 0; p < 8; ++p) {
      const int r = wave * 8 + p;
      const float4* src = x + ((size_t)rb * 32 + r) * K4 + ks * 128 + lane * 2;
      float4 a = src[0], c = src[1];
      lds[(wloc + r * 4) ^ swz] = pack8(a, c);
    }
    __syncthreads();
    const size_t gbase = (size_t)rb * 4096 + ks * 512;
#pragma unroll
    for (int q = 0; q < 2; ++q) {
      const int blk = q * 256 + t;
      const int sblk = blk ^ ((blk >> 5) & 7);
      xq[gbase + blk] = *(const uint4*)&lds[sblk * 4];
    }
  }
}

// async global->LDS, 16B per lane (wave-uniform base + lane*16)
__device__ __forceinline__ void load16(const uint8_t* g, uint8_t* l) {
  __builtin_amdgcn_global_load_lds(
      (const __attribute__((address_space(1))) uint32_t*)(uintptr_t)g,
      (__attribute__((address_space(3))) uint32_t*)(uintptr_t)l,
      16, 0, 0);
}

// ---------------- GEMM: C[m,n] = scale[n] * sum_k A[m,k]*B[n,k] ----------------
// A, B in fragment order (see header comment). mfma_scale 32x32x64 f8f6f4, FMT=4,
// scales pinned to 1.0 (e8m0 0x7F). fp32 accumulate exact for +-1 sums.
// 256 threads = 4 waves in 2x2; each wave does 64x64 via 2x2 of 32x32 tiles.
__global__ __launch_bounds__(256, 3) void gemm_bt_kernel(
    const uint8_t* __restrict__ A, const uint8_t* __restrict__ B,
    const float* __restrict__ scale, float* __restrict__ C,
    int M, int N, int K) {
  __shared__ __align__(16) uint8_t As[BM * 64];  // 4 groups x 128 frags x 16 B
  __shared__ __align__(16) uint8_t Bs[BN * 64];

  const int tid = threadIdx.x;
  const int lane = tid & 63;
  const int wave = tid >> 6;
  const int waveM = wave & 1;
  const int waveN = wave >> 1;
  const int kbT = K >> 7;  // K-tile iterations (64 B of K per iter)

  // XCD-aware bijective swizzle (nwg = gridDim.x*gridDim.y, divisible by 8)
  const int nwg = gridDim.x * gridDim.y;
  const int id = blockIdx.y * gridDim.x + blockIdx.x;
  const int swz = (id & 7) * (nwg >> 3) + (id >> 3);
  const int bx = swz % gridDim.x;
  const int by = swz / gridDim.x;

  // staging: wave w owns 32-row group w; 2 contiguous 1024-B loads per K-iter
  const uint8_t* aG = A + ((size_t)(by * 4 + wave) * kbT) * 2048 + lane * 16;
  const uint8_t* bG = B + ((size_t)(bx * 4 + wave) * kbT) * 2048 + lane * 16;
  uint8_t* aL = As + wave * 2048 + lane * 16;
  uint8_t* bL = Bs + wave * 2048 + lane * 16;

  // fragment reads: group (2*waveM+mi), p2 = s*64 + lane  ->  lane-linear
  const uint8_t* aF = As + waveM * 4096 + lane * 16;
  const uint8_t* bF = Bs + waveN * 4096 + lane * 16;

  f32x16 acc[2][2] = {};
  // persistent v8i32 operands; high 4 regs stay zero (fp4 uses low 4 only)
  i32x8 aop[2] = {}, bop[2] = {};

  for (int i = 0; i < kbT; ++i) {
    __syncthreads();  // previous iter's LDS reads done before overwrite
    const size_t o = (size_t)i * 2048;
    load16(aG + o, aL);
    load16(aG + o + 1024, aL + 1024);
    load16(bG + o, bL);
    load16(bG + o + 1024, bL + 1024);
    __syncthreads();  // staging complete (vmcnt drained before barrier)

#pragma unroll
    for (int s = 0; s < 2; ++s) {  // two K=64 MFMA steps per 64-B row tile
#pragma unroll
      for (int mi = 0; mi < 2; ++mi) {
        i32x4 t4 = *(const i32x4*)(aF + mi * 2048 + s * 1024);
        aop[mi].s0 = t4.x; aop[mi].s1 = t4.y; aop[mi].s2 = t4.z; aop[mi].s3 = t4.w;
      }
#pragma unroll
      for (int ni = 0; ni < 2; ++ni) {
        i32x4 t4 = *(const i32x4*)(bF + ni * 2048 + s * 1024);
        bop[ni].s0 = t4.x; bop[ni].s1 = t4.y; bop[ni].s2 = t4.z; bop[ni].s3 = t4.w;
      }
#pragma unroll
      for (int mi = 0; mi < 2; ++mi)
#pragma unroll
        for (int ni = 0; ni < 2; ++ni)
          acc[mi][ni] = __builtin_amdgcn_mfma_scale_f32_32x32x64_f8f6f4(
              aop[mi], bop[ni], acc[mi][ni],
              /*cbsz=fp4*/ 4, /*blgp=fp4*/ 4,
              /*opsel_a*/ 0, 0x7f7f7f7f, /*opsel_b*/ 0, 0x7f7f7f7f);
    }
  }

  // epilogue: 32x32 C/D layout col=lane&31, row=(reg&3)+8*(reg>>2)+4*(lane>>5)
  const int cCol = bx * BN + waveN * 64 + (lane & 31);
  const int cRowBase = by * BM + waveM * 64 + 4 * (lane >> 5);
  float sc[2];
#pragma unroll
  for (int ni = 0; ni < 2; ++ni) sc[ni] = scale[cCol + ni * 32];
#pragma unroll
  for (int mi = 0; mi < 2; ++mi)
#pragma unroll
    for (int ni = 0; ni < 2; ++ni)
#pragma unroll
      for (int r = 0; r < 16; ++r) {
        int row = cRowBase + mi * 32 + (r & 3) + 8 * (r >> 2);
        C[(size_t)row * N + cCol + ni * 32] = acc[mi][ni][r] * sc[ni];
      }
}

// ---------------- fallback (only if ws too small): exact, slow ----------------
__global__ void fallback_gemm(const float* __restrict__ X, const float* __restrict__ W,
                              float* __restrict__ C, int M, int N, int K) {
  __shared__ float xs[16][65];
  __shared__ float ws[16][65];
  __shared__ float wabs[256];
  __shared__ float scl[16];
  const int tx = threadIdx.x, ty = threadIdx.y;
  const int t = ty * 16 + tx;
  float acc = 0.f, wa = 0.f;
  for (int k0 = 0; k0 < K; k0 += 64) {
    __syncthreads();
#pragma unroll
    for (int j = 0; j < 4; ++j) {
      int e = t * 4 + j;
      int r = e >> 6, c = e & 63;
      float xv = X[(size_t)(blockIdx.y * 16 + r) * K + k0 + c];
      xs[r][c] = xv > 0.f ? 1.f : (xv < 0.f ? -1.f : 0.f);
      float wv = W[(size_t)(blockIdx.x * 16 + r) * K + k0 + c];
      ws[r][c] = wv > 0.f ? 1.f : (wv < 0.f ? -1.f : 0.f);
      wa += fabsf(wv);
    }
    __syncthreads();
#pragma unroll 8
    for (int k = 0; k < 64; ++k) acc += xs[ty][k] * ws[tx][k];
  }
  wabs[t] = wa;
  __syncthreads();
  for (int s2 = 8; s2 > 0; s2 >>= 1) {
    if (tx < s2) wabs[t] += wabs[t + s2];
    __syncthreads();
  }
  if (tx == 0) scl[ty] = wabs[t] / (float)K;
  __syncthreads();
  C[(size_t)(blockIdx.y * 16 + ty) * N + (blockIdx.x * 16 + tx)] = acc * scl[tx];
}

extern "C" void kernel_launch(void* const* d_in, const int* in_sizes, int n_in,
                              void* d_out, int out_size, void* d_ws, size_t ws_size,
                              hipStream_t stream) {
  const float* x = (const float*)d_in[0];
  const float* w = (const float*)d_in[1];
  float* out = (float*)d_out;

  const int K = 4096;
  const int N = in_sizes[1] / K;  // 4096
  const int M = in_sizes[0] / K;  // 8192

  size_t need = (size_t)M * (K / 2) + (size_t)N * (K / 2) + (size_t)N * sizeof(float);
  if (ws_size >= need) {
    uint8_t* Xq = (uint8_t*)d_ws;
    uint8_t* Wq = Xq + (size_t)M * (K / 2);
    float* scale = (float*)(Wq + (size_t)N * (K / 2));

    const int wBlocks = N / 32;                          // 128 rowblocks
    const int xBlocks = (int)(((size_t)M * K) / 16384);  // 2048 slabs
    quant_fused_kernel<<<wBlocks + xBlocks, 256, 0, stream>>>(
        (const float4*)x, (uint4*)Xq, (const float4*)w, (uint4*)Wq,
        scale, wBlocks, K);

    dim3 grid(N / BN, M / BM);
    gemm_bt_kernel<<<grid, 256, 0, stream>>>(Xq, Wq, scale, out, M, N, K);
  } else {
    dim3 grid(N / 16, M / 16);
    fallback_gemm<<<grid, dim3(16, 16), 0, stream>>>(x, w, out, M, N, K);
  }
}